// Round 5
// baseline (242.225 us; speedup 1.0000x reference)
//
#include <hip/hip_runtime.h>

// Problem constants (fixed by the reference file).
static constexpr int B = 16;
static constexpr int N = 250000;   // 15625 * 16
static constexpr int F = 500000;
static constexpr int C3 = 3 * F;   // corners = 1,500,000
static constexpr int E = 6 * F;    // directed edges (CSR fallback)
static constexpr int RW = 48;      // ushorts per vt row: 3 comps * 16 batches (96 B)
static constexpr int CAP = 24;     // pair capacity/vertex (Poisson(6); P(>=24) ~ 3e-11)
static constexpr int PF  = 12;     // gather prefetch depth (P(pairs>12) ~ 0.8%)
static constexpr int SLICE = N / 8;          // 31250 vertices per XCD slice
static constexpr int SETUP_G = ((F + 255) / 256) * 8;   // 1954 * 8 = 15632 blocks
static_assert(SETUP_G >= N / 16, "setup grid must still cover the transpose");

// deg zero-fill: N uints = 1,000,000 B = 62,500 uint4
static constexpr int DEG_U4 = (N * 4) / 16;  // 62500
static_assert(DEG_U4 * 16 == N * 4, "deg must be uint4-divisible");

// ---- DIRECT layout (bytes): vt | deg (compact) | adjp PLANE-MAJOR ----
// adjp[pi * N + n] (pi < CAP). Plane-major (R4): setup 96 -> 83 us, atomic
// rate 0.8 -> 0.94/cy/XCD — the "atomic ceiling" moved with adj layout, so
// the drag is L2 pressure from the adj scatter path, not the atomic pipe.
// R5: adj writes are NONTEMPORAL (write-once, read-next-kernel) to stop the
// RFO/dirty-line thrash (R4 WRITE_SIZE: 1.5M writes x 64 B = 96 MB unmerged).
static constexpr size_t D_VT  = 0;                                   // 24,000,000
static constexpr size_t D_DEG = (size_t)N * RW * 2;                  // 24,000,000 (+1 MB)
static constexpr size_t D_ADJ = D_DEG + (size_t)N * 4;               // 25,000,000
static constexpr size_t D_NEED = D_ADJ + (size_t)N * CAP * 8;        // 73,000,000

// ---- CSR fallback layout (R5-proven structure) ----
static constexpr size_t C_VT  = 0;
static constexpr size_t C_ADJ = (size_t)N * RW * 2;
static constexpr size_t C_DEG = C_ADJ + (size_t)E * sizeof(int);
static constexpr size_t C_CNT = C_DEG + (size_t)N * sizeof(unsigned);
static constexpr size_t C_STA = C_CNT + 256;
static constexpr size_t C_RNK = C_STA + (size_t)N * sizeof(unsigned);

__device__ __forceinline__ unsigned short f2bf(float f) {
    unsigned u = __float_as_uint(f);
    return (unsigned short)((u + 0x7FFFu + ((u >> 16) & 1u)) >> 16);  // RNE
}

__device__ __forceinline__ long long pack_pair(int p0, int p1) {
    return (long long)((unsigned long long)(unsigned)p0 |
                       ((unsigned long long)(unsigned)p1 << 32));
}

// Zero deg with a compute kernel (1 MB), not hipMemsetAsync (SDMA, ~13 us).
__global__ __launch_bounds__(256) void uls_zero_deg(uint4* __restrict__ degv) {
    for (int i = blockIdx.x * 256 + threadIdx.x; i < DEG_U4;
         i += gridDim.x * 256)
        degv[i] = make_uint4(0u, 0u, 0u, 0u);
}

// ================= DIRECT path =================

// Fused: transpose (B,N,3)fp32 -> (N,3,16)bf16  +  slice-partitioned corner alloc.
// slice = blockIdx % 8: all atomics/writes to a given deg/adj line issue from
// ONE XCD under the default round-robin blockIdx->XCD map (R1: 120 -> 97 us).
__global__ __launch_bounds__(256) void uls_setup_direct(
    const float* __restrict__ vert, const int* __restrict__ faces,
    unsigned short* __restrict__ vt, unsigned* __restrict__ deg,
    long long* __restrict__ adjp)
{
    __shared__ unsigned short lus[16 * RW];
    int t   = threadIdx.x;
    int bid = blockIdx.x;
    int s   = bid & 7;            // vertex slice (XCD-aligned under round-robin)
    int g   = bid >> 3;           // rank within slice-group
    int f   = g * 256 + t;        // one face per thread per slice-scan
    bool f_ok = (f < F);
    unsigned lo = (unsigned)(s * SLICE);

    int a = 0, b2 = 0, c2 = 0;
    if (f_ok) {
        a  = faces[3 * f + 0];
        b2 = faces[3 * f + 1];
        c2 = faces[3 * f + 2];
    }
    bool k0 = f_ok && ((unsigned)a  - lo < (unsigned)SLICE);
    bool k1 = f_ok && ((unsigned)b2 - lo < (unsigned)SLICE);
    bool k2 = f_ok && ((unsigned)c2 - lo < (unsigned)SLICE);
    unsigned r0 = 0, r1 = 0, r2 = 0;
    if (k0) r0 = atomicAdd(&deg[a],  2u);   // slot allocator (compact counters)
    if (k1) r1 = atomicAdd(&deg[b2], 2u);
    if (k2) r2 = atomicAdd(&deg[c2], 2u);

    // transpose part (blocks < N/16); atomic latency hides behind this
    if (bid < N / 16) {
        int n0 = bid * 16;
        int bb = t >> 4, v = t & 15;
        const float* sp = vert + (size_t)bb * (N * 3) + (size_t)(n0 + v) * 3;
        lus[v * RW + 0 * 16 + bb] = f2bf(sp[0]);
        lus[v * RW + 1 * 16 + bb] = f2bf(sp[1]);
        lus[v * RW + 2 * 16 + bb] = f2bf(sp[2]);
        __syncthreads();
        const uint2* lu2 = (const uint2*)lus;
        uint2* d2 = (uint2*)(vt + (size_t)n0 * RW);
        if (t < 192) d2[t] = lu2[t];          // coalesced 1536 B per block
    }

    // pair writes last, NONTEMPORAL (write-once; keep them out of L2's way)
    if (k0) { unsigned pi = r0 >> 1; if (pi < (unsigned)CAP)
        __builtin_nontemporal_store(pack_pair(b2, c2), &adjp[(size_t)pi * N + a]); }
    if (k1) { unsigned pi = r1 >> 1; if (pi < (unsigned)CAP)
        __builtin_nontemporal_store(pack_pair(a, c2), &adjp[(size_t)pi * N + b2]); }
    if (k2) { unsigned pi = r2 >> 1; if (pi < (unsigned)CAP)
        __builtin_nontemporal_store(pack_pair(a, b2), &adjp[(size_t)pi * N + c2]); }
}

// 4 lanes per vertex; lane q owns batches 4q..4q+3 via uint2 (8 B) loads.
__device__ __forceinline__ void acc_row(const unsigned short* __restrict__ r,
                                        int q, float (&acc)[3][4]) {
#pragma unroll
    for (int cc = 0; cc < 3; ++cc) {
        uint2 u = *(const uint2*)(r + cc * 16 + 4 * q);
        acc[cc][0] += __uint_as_float(u.x << 16);
        acc[cc][1] += __uint_as_float(u.x & 0xFFFF0000u);
        acc[cc][2] += __uint_as_float(u.y << 16);
        acc[cc][3] += __uint_as_float(u.y & 0xFFFF0000u);
    }
}

// R5: break the adj->row serial chain. Issue up to PF=12 predicated adj plane
// loads up-front (ONE L3 round-trip), then stream all row loads behind them.
// adj/deg loads are nontemporal (read-once; don't evict vt from L2).
__global__ __launch_bounds__(256) void uls_gather_direct(
    const unsigned short* __restrict__ vt, const long long* __restrict__ adjp,
    const unsigned* __restrict__ deg, float* __restrict__ out)
{
    __shared__ float lds[16 * 65];
    int t = threadIdx.x;
    int q = t & 3;
    int v = t >> 2;
    int n = blockIdx.x * 64 + v;
    bool n_ok = (n < N);

    unsigned d = n_ok ? __builtin_nontemporal_load(&deg[n]) : 0u;
    if (d > 2u * CAP) d = 2u * CAP;
    unsigned pairs = d >> 1;              // <= 24
    const long long* ap = adjp + n;       // this vertex's column

    // self row hoisted: 3 more loads in flight during the gather loop
    float self[3][4] = {{0,0,0,0},{0,0,0,0},{0,0,0,0}};
    if (n_ok) {
        const unsigned short* rs = vt + (size_t)n * RW;
#pragma unroll
        for (int cc = 0; cc < 3; ++cc) {
            uint2 u = *(const uint2*)(rs + cc * 16 + 4 * q);
            self[cc][0] = __uint_as_float(u.x << 16);
            self[cc][1] = __uint_as_float(u.x & 0xFFFF0000u);
            self[cc][2] = __uint_as_float(u.y << 16);
            self[cc][3] = __uint_as_float(u.y & 0xFFFF0000u);
        }
    }

    // predicated up-front adj loads (exec-masked: off lanes issue nothing)
    long long pv[PF];
#pragma unroll
    for (int j = 0; j < PF; ++j)
        pv[j] = (j < (int)pairs)
              ? __builtin_nontemporal_load(&ap[(size_t)j * N]) : 0ll;

    float acc[3][4] = {{0,0,0,0},{0,0,0,0},{0,0,0,0}};
#pragma unroll
    for (int j = 0; j < PF; ++j) {
        if (j < (int)pairs) {
            acc_row(vt + (size_t)(unsigned)pv[j] * RW, q, acc);
            acc_row(vt + (size_t)(unsigned)(pv[j] >> 32) * RW, q, acc);
        }
    }
    for (unsigned j = PF; j < pairs; ++j) {     // Poisson tail, P ~ 0.8%
        long long v0 = __builtin_nontemporal_load(&ap[(size_t)j * N]);
        acc_row(vt + (size_t)(unsigned)v0 * RW, q, acc);
        acc_row(vt + (size_t)(unsigned)(v0 >> 32) * RW, q, acc);
    }

    if (n_ok) {
        float inv = 1.0f / fmaxf((float)d, 1.0f);
#pragma unroll
        for (int k = 0; k < 4; ++k) {
            float lx = acc[0][k] * inv - self[0][k];
            float ly = acc[1][k] * inv - self[1][k];
            float lz = acc[2][k] * inv - self[2][k];
            lds[(4 * q + k) * 65 + v] = sqrtf(lx * lx + ly * ly + lz * lz);
        }
    }
    __syncthreads();
    int vo = t & 63;
    int nn = blockIdx.x * 64 + vo;
    if (nn < N) {
#pragma unroll
        for (int k = 0; k < 4; ++k) {
            int bo = (t >> 6) + 4 * k;
            __builtin_nontemporal_store(lds[bo * 65 + vo],
                                        &out[(size_t)bo * N + nn]);
        }
    }
}

// ================= CSR fallback (used only if ws < 73 MB) =================

__global__ __launch_bounds__(256) void uls_setup_csr(
    const float* __restrict__ vert, const int* __restrict__ faces,
    unsigned short* __restrict__ vt, unsigned* __restrict__ deg,
    unsigned* __restrict__ rank)
{
    __shared__ unsigned short lus[16 * RW];
    int t = threadIdx.x;
    int n0 = blockIdx.x * 16;
    int b = t >> 4, v = t & 15;
    int e = blockIdx.x * 256 + t;
    unsigned rv = 0;
    bool e_ok = (e < C3);
    int dst = e_ok ? faces[e] : 0;
    if (e_ok) rv = atomicAdd(&deg[dst], 2u);
    const float* s = vert + (size_t)b * (N * 3) + (size_t)(n0 + v) * 3;
    lus[v * RW + 0 * 16 + b] = f2bf(s[0]);
    lus[v * RW + 1 * 16 + b] = f2bf(s[1]);
    lus[v * RW + 2 * 16 + b] = f2bf(s[2]);
    __syncthreads();
    const uint2* lu2 = (const uint2*)lus;
    uint2* d2 = (uint2*)(vt + (size_t)n0 * RW);
    if (t < 192) d2[t] = lu2[t];
    if (e_ok) rank[e] = rv;
}

__global__ __launch_bounds__(256) void uls_alloc(
    const unsigned* __restrict__ deg, unsigned* __restrict__ start,
    unsigned* __restrict__ counter)
{
    __shared__ unsigned s[256];
    __shared__ unsigned base;
    int t = threadIdx.x;
    int n = blockIdx.x * 256 + t;
    unsigned d = (n < N) ? deg[n] : 0u;
    s[t] = d;
    __syncthreads();
    for (int off = 1; off < 256; off <<= 1) {
        unsigned v = (t >= off) ? s[t - off] : 0u;
        __syncthreads();
        s[t] += v;
        __syncthreads();
    }
    if (t == 255) base = atomicAdd(counter, s[255]);
    __syncthreads();
    if (n < N) start[n] = base + (s[t] - d);
}

__global__ __launch_bounds__(256) void uls_fill(
    const int* __restrict__ faces, const unsigned* __restrict__ start,
    const unsigned* __restrict__ rank, int* __restrict__ adj)
{
    int e = blockIdx.x * 256 + threadIdx.x;
    if (e >= C3) return;
    int f = e / 3;
    int c = e - 3 * f;
    int a  = faces[3 * f + 0];
    int b  = faces[3 * f + 1];
    int cc = faces[3 * f + 2];
    int dst = (c == 0) ? a : (c == 1) ? b : cc;
    int p0  = (c == 0) ? b : a;
    int p1  = (c == 2) ? b : cc;
    unsigned p = start[dst] + rank[e];
    *(int2*)(adj + p) = make_int2(p0, p1);
}

__global__ __launch_bounds__(256) void uls_gather_csr(
    const unsigned short* __restrict__ vt, const int* __restrict__ adj,
    const unsigned* __restrict__ start, const unsigned* __restrict__ deg,
    float* __restrict__ out)
{
    __shared__ float lds[16 * 65];
    int t = threadIdx.x;
    int q = t & 3;
    int v = t >> 2;
    int n = blockIdx.x * 64 + v;
    bool n_ok = (n < N);
    unsigned d  = n_ok ? deg[n]   : 0u;
    unsigned s0 = n_ok ? start[n] : 0u;
    float acc[3][4] = {{0,0,0,0},{0,0,0,0},{0,0,0,0}};
    unsigned j = 0;
    for (; j + 4 <= d; j += 4) {
        int2 p0 = *(const int2*)(adj + s0 + j);
        int2 p1 = *(const int2*)(adj + s0 + j + 2);
        acc_row(vt + (size_t)p0.x * RW, q, acc);
        acc_row(vt + (size_t)p0.y * RW, q, acc);
        acc_row(vt + (size_t)p1.x * RW, q, acc);
        acc_row(vt + (size_t)p1.y * RW, q, acc);
    }
    if (j < d) {
        int2 p0 = *(const int2*)(adj + s0 + j);
        acc_row(vt + (size_t)p0.x * RW, q, acc);
        acc_row(vt + (size_t)p0.y * RW, q, acc);
    }
    if (n_ok) {
        float self[3][4];
        const unsigned short* rs = vt + (size_t)n * RW;
#pragma unroll
        for (int cc = 0; cc < 3; ++cc) {
            uint2 u = *(const uint2*)(rs + cc * 16 + 4 * q);
            self[cc][0] = __uint_as_float(u.x << 16);
            self[cc][1] = __uint_as_float(u.x & 0xFFFF0000u);
            self[cc][2] = __uint_as_float(u.y << 16);
            self[cc][3] = __uint_as_float(u.y & 0xFFFF0000u);
        }
        float inv = 1.0f / fmaxf((float)d, 1.0f);
#pragma unroll
        for (int k = 0; k < 4; ++k) {
            float lx = acc[0][k] * inv - self[0][k];
            float ly = acc[1][k] * inv - self[1][k];
            float lz = acc[2][k] * inv - self[2][k];
            lds[(4 * q + k) * 65 + v] = sqrtf(lx * lx + ly * ly + lz * lz);
        }
    }
    __syncthreads();
    int vo = t & 63;
    int nn = blockIdx.x * 64 + vo;
    if (nn < N) {
#pragma unroll
        for (int k = 0; k < 4; ++k) {
            int bo = (t >> 6) + 4 * k;
            out[(size_t)bo * N + nn] = lds[bo * 65 + vo];
        }
    }
}

// ================= launcher =================

extern "C" void kernel_launch(void* const* d_in, const int* in_sizes, int n_in,
                              void* d_out, int out_size, void* d_ws, size_t ws_size,
                              hipStream_t stream) {
    const float* vert  = (const float*)d_in[0];
    const int*   faces = (const int*)d_in[1];
    float* out = (float*)d_out;
    char* ws = (char*)d_ws;

    if (ws_size >= D_NEED) {
        unsigned short* vt  = (unsigned short*)(ws + D_VT);
        unsigned*       deg = (unsigned*)(ws + D_DEG);
        long long*      adj = (long long*)(ws + D_ADJ);
        uls_zero_deg<<<(DEG_U4 + 255) / 256, 256, 0, stream>>>((uint4*)deg);
        uls_setup_direct<<<SETUP_G, 256, 0, stream>>>(vert, faces, vt, deg, adj);
        uls_gather_direct<<<(N + 63) / 64, 256, 0, stream>>>(vt, adj, deg, out);
    } else {
        // CSR pipeline (proven at 264.6 us)
        unsigned short* vt      = (unsigned short*)(ws + C_VT);
        int*            adj     = (int*)(ws + C_ADJ);
        unsigned*       deg     = (unsigned*)(ws + C_DEG);
        unsigned*       counter = (unsigned*)(ws + C_CNT);
        unsigned*       start   = (unsigned*)(ws + C_STA);
        unsigned*       rank    = (unsigned*)(ws + C_RNK);
        hipMemsetAsync(ws + C_DEG, 0, (C_CNT + 256) - C_DEG, stream);
        uls_setup_csr<<<N / 16, 256, 0, stream>>>(vert, faces, vt, deg, rank);
        uls_alloc<<<(N + 255) / 256, 256, 0, stream>>>(deg, start, counter);
        uls_fill<<<(C3 + 255) / 256, 256, 0, stream>>>(faces, start, rank, adj);
        uls_gather_csr<<<(N + 63) / 64, 256, 0, stream>>>(vt, adj, start, deg, out);
    }
}

// Round 7
// 229.097 us; speedup vs baseline: 1.0573x; 1.0573x over previous
//
#include <hip/hip_runtime.h>

// Problem constants (fixed by the reference file).
static constexpr int B = 16;
static constexpr int N = 250000;   // 15625 * 16
static constexpr int F = 500000;
static constexpr int C3 = 3 * F;   // corners = 1,500,000
static constexpr int E = 6 * F;    // directed edges (CSR fallback)
static constexpr int RW = 48;      // ushorts per vt row: 3 comps * 16 batches (96 B)
static constexpr int CAP = 24;     // pair capacity/vertex (Poisson(6); P(>=24) ~ 3e-11)
static constexpr int PF  = 12;     // gather prefetch depth (P(pairs>12) ~ 0.8%)
static constexpr int SLICE = N / 8;          // 31250 vertices per XCD slice
static constexpr int SETUP_G = ((F + 255) / 256) * 8;   // 1954 * 8 = 15632 blocks
static_assert(SETUP_G >= N / 16, "setup grid must still cover the transpose");

// deg zero-fill: N uints = 1,000,000 B = 62,500 uint4
static constexpr int DEG_U4 = (N * 4) / 16;  // 62500
static_assert(DEG_U4 * 16 == N * 4, "deg must be uint4-divisible");

// ---- DIRECT layout (bytes): vt | deg (compact) | adjp PLANE-MAJOR ----
// adjp[pi * N + n] (pi < CAP).
// R5 ERRATum: nt on adj STORES regressed (83->90 us, WRITE 121->134 MB): nt
// defeats the L2 write-merging that WAS happening. R6 inverts: adj stores are
// normal (merge in L2); the pure STREAMING traffic (vert reads, vt writes) is
// nontemporal so it stops evicting the ~3 MB/XCD adj+deg hot set.
// (R6 compile fix: nontemporal builtins reject HIP_vector_type pointers —
// route the 8 B vt store through unsigned long long.)
static constexpr size_t D_VT  = 0;                                   // 24,000,000
static constexpr size_t D_DEG = (size_t)N * RW * 2;                  // 24,000,000 (+1 MB)
static constexpr size_t D_ADJ = D_DEG + (size_t)N * 4;               // 25,000,000
static constexpr size_t D_NEED = D_ADJ + (size_t)N * CAP * 8;        // 73,000,000

// ---- CSR fallback layout (R5-proven structure) ----
static constexpr size_t C_VT  = 0;
static constexpr size_t C_ADJ = (size_t)N * RW * 2;
static constexpr size_t C_DEG = C_ADJ + (size_t)E * sizeof(int);
static constexpr size_t C_CNT = C_DEG + (size_t)N * sizeof(unsigned);
static constexpr size_t C_STA = C_CNT + 256;
static constexpr size_t C_RNK = C_STA + (size_t)N * sizeof(unsigned);

__device__ __forceinline__ unsigned short f2bf(float f) {
    unsigned u = __float_as_uint(f);
    return (unsigned short)((u + 0x7FFFu + ((u >> 16) & 1u)) >> 16);  // RNE
}

__device__ __forceinline__ long long pack_pair(int p0, int p1) {
    return (long long)((unsigned long long)(unsigned)p0 |
                       ((unsigned long long)(unsigned)p1 << 32));
}

// Zero deg with a compute kernel (1 MB), not hipMemsetAsync (SDMA, ~13 us).
__global__ __launch_bounds__(256) void uls_zero_deg(uint4* __restrict__ degv) {
    for (int i = blockIdx.x * 256 + threadIdx.x; i < DEG_U4;
         i += gridDim.x * 256)
        degv[i] = make_uint4(0u, 0u, 0u, 0u);
}

// ================= DIRECT path =================

// Fused: transpose (B,N,3)fp32 -> (N,3,16)bf16  +  slice-partitioned corner alloc.
// slice = blockIdx % 8: all atomics/writes to a given deg/adj line issue from
// ONE XCD under the default round-robin blockIdx->XCD map (R1: 120 -> 97 us).
// Streaming traffic (vert in, vt out) is NONTEMPORAL: keep L2 for deg + adj.
__global__ __launch_bounds__(256) void uls_setup_direct(
    const float* __restrict__ vert, const int* __restrict__ faces,
    unsigned short* __restrict__ vt, unsigned* __restrict__ deg,
    long long* __restrict__ adjp)
{
    __shared__ unsigned short lus[16 * RW];
    int t   = threadIdx.x;
    int bid = blockIdx.x;
    int s   = bid & 7;            // vertex slice (XCD-aligned under round-robin)
    int g   = bid >> 3;           // rank within slice-group
    int f   = g * 256 + t;        // one face per thread per slice-scan
    bool f_ok = (f < F);
    unsigned lo = (unsigned)(s * SLICE);

    int a = 0, b2 = 0, c2 = 0;
    if (f_ok) {                   // faces: normal loads (re-read 8x, L3-hot)
        a  = faces[3 * f + 0];
        b2 = faces[3 * f + 1];
        c2 = faces[3 * f + 2];
    }
    bool k0 = f_ok && ((unsigned)a  - lo < (unsigned)SLICE);
    bool k1 = f_ok && ((unsigned)b2 - lo < (unsigned)SLICE);
    bool k2 = f_ok && ((unsigned)c2 - lo < (unsigned)SLICE);
    unsigned r0 = 0, r1 = 0, r2 = 0;
    if (k0) r0 = atomicAdd(&deg[a],  2u);   // slot allocator (compact counters)
    if (k1) r1 = atomicAdd(&deg[b2], 2u);
    if (k2) r2 = atomicAdd(&deg[c2], 2u);

    // transpose part (blocks < N/16); atomic latency hides behind this.
    // vert reads / vt writes are read-once/write-once -> nontemporal.
    if (bid < N / 16) {
        int n0 = bid * 16;
        int bb = t >> 4, v = t & 15;
        const float* sp = vert + (size_t)bb * (N * 3) + (size_t)(n0 + v) * 3;
        lus[v * RW + 0 * 16 + bb] = f2bf(__builtin_nontemporal_load(&sp[0]));
        lus[v * RW + 1 * 16 + bb] = f2bf(__builtin_nontemporal_load(&sp[1]));
        lus[v * RW + 2 * 16 + bb] = f2bf(__builtin_nontemporal_load(&sp[2]));
        __syncthreads();
        const unsigned long long* lu8 = (const unsigned long long*)lus;
        unsigned long long* d8 = (unsigned long long*)(vt + (size_t)n0 * RW);
        if (t < 192) __builtin_nontemporal_store(lu8[t], &d8[t]);
    }

    // pair writes last, NORMAL stores (multi-write/line: let L2 merge them)
    if (k0) { unsigned pi = r0 >> 1; if (pi < (unsigned)CAP)
        adjp[(size_t)pi * N + a]  = pack_pair(b2, c2); }
    if (k1) { unsigned pi = r1 >> 1; if (pi < (unsigned)CAP)
        adjp[(size_t)pi * N + b2] = pack_pair(a, c2); }
    if (k2) { unsigned pi = r2 >> 1; if (pi < (unsigned)CAP)
        adjp[(size_t)pi * N + c2] = pack_pair(a, b2); }
}

// 4 lanes per vertex; lane q owns batches 4q..4q+3 via uint2 (8 B) loads.
__device__ __forceinline__ void acc_row(const unsigned short* __restrict__ r,
                                        int q, float (&acc)[3][4]) {
#pragma unroll
    for (int cc = 0; cc < 3; ++cc) {
        uint2 u = *(const uint2*)(r + cc * 16 + 4 * q);
        acc[cc][0] += __uint_as_float(u.x << 16);
        acc[cc][1] += __uint_as_float(u.x & 0xFFFF0000u);
        acc[cc][2] += __uint_as_float(u.y << 16);
        acc[cc][3] += __uint_as_float(u.y & 0xFFFF0000u);
    }
}

// Up-front predicated adj plane loads (one L3 round-trip), rows streamed behind.
__global__ __launch_bounds__(256) void uls_gather_direct(
    const unsigned short* __restrict__ vt, const long long* __restrict__ adjp,
    const unsigned* __restrict__ deg, float* __restrict__ out)
{
    __shared__ float lds[16 * 65];
    int t = threadIdx.x;
    int q = t & 3;
    int v = t >> 2;
    int n = blockIdx.x * 64 + v;
    bool n_ok = (n < N);

    unsigned d = n_ok ? __builtin_nontemporal_load(&deg[n]) : 0u;
    if (d > 2u * CAP) d = 2u * CAP;
    unsigned pairs = d >> 1;              // <= 24
    const long long* ap = adjp + n;       // this vertex's column

    // self row hoisted: 3 more loads in flight during the gather loop
    float self[3][4] = {{0,0,0,0},{0,0,0,0},{0,0,0,0}};
    if (n_ok) {
        const unsigned short* rs = vt + (size_t)n * RW;
#pragma unroll
        for (int cc = 0; cc < 3; ++cc) {
            uint2 u = *(const uint2*)(rs + cc * 16 + 4 * q);
            self[cc][0] = __uint_as_float(u.x << 16);
            self[cc][1] = __uint_as_float(u.x & 0xFFFF0000u);
            self[cc][2] = __uint_as_float(u.y << 16);
            self[cc][3] = __uint_as_float(u.y & 0xFFFF0000u);
        }
    }

    // predicated up-front adj loads (exec-masked: off lanes issue nothing)
    long long pv[PF];
#pragma unroll
    for (int j = 0; j < PF; ++j)
        pv[j] = (j < (int)pairs)
              ? __builtin_nontemporal_load(&ap[(size_t)j * N]) : 0ll;

    float acc[3][4] = {{0,0,0,0},{0,0,0,0},{0,0,0,0}};
#pragma unroll
    for (int j = 0; j < PF; ++j) {
        if (j < (int)pairs) {
            acc_row(vt + (size_t)(unsigned)pv[j] * RW, q, acc);
            acc_row(vt + (size_t)(unsigned)(pv[j] >> 32) * RW, q, acc);
        }
    }
    for (unsigned j = PF; j < pairs; ++j) {     // Poisson tail, P ~ 0.8%
        long long v0 = __builtin_nontemporal_load(&ap[(size_t)j * N]);
        acc_row(vt + (size_t)(unsigned)v0 * RW, q, acc);
        acc_row(vt + (size_t)(unsigned)(v0 >> 32) * RW, q, acc);
    }

    if (n_ok) {
        float inv = 1.0f / fmaxf((float)d, 1.0f);
#pragma unroll
        for (int k = 0; k < 4; ++k) {
            float lx = acc[0][k] * inv - self[0][k];
            float ly = acc[1][k] * inv - self[1][k];
            float lz = acc[2][k] * inv - self[2][k];
            lds[(4 * q + k) * 65 + v] = sqrtf(lx * lx + ly * ly + lz * lz);
        }
    }
    __syncthreads();
    int vo = t & 63;
    int nn = blockIdx.x * 64 + vo;
    if (nn < N) {
#pragma unroll
        for (int k = 0; k < 4; ++k) {
            int bo = (t >> 6) + 4 * k;
            __builtin_nontemporal_store(lds[bo * 65 + vo],
                                        &out[(size_t)bo * N + nn]);
        }
    }
}

// ================= CSR fallback (used only if ws < 73 MB) =================

__global__ __launch_bounds__(256) void uls_setup_csr(
    const float* __restrict__ vert, const int* __restrict__ faces,
    unsigned short* __restrict__ vt, unsigned* __restrict__ deg,
    unsigned* __restrict__ rank)
{
    __shared__ unsigned short lus[16 * RW];
    int t = threadIdx.x;
    int n0 = blockIdx.x * 16;
    int b = t >> 4, v = t & 15;
    int e = blockIdx.x * 256 + t;
    unsigned rv = 0;
    bool e_ok = (e < C3);
    int dst = e_ok ? faces[e] : 0;
    if (e_ok) rv = atomicAdd(&deg[dst], 2u);
    const float* s = vert + (size_t)b * (N * 3) + (size_t)(n0 + v) * 3;
    lus[v * RW + 0 * 16 + b] = f2bf(s[0]);
    lus[v * RW + 1 * 16 + b] = f2bf(s[1]);
    lus[v * RW + 2 * 16 + b] = f2bf(s[2]);
    __syncthreads();
    const uint2* lu2 = (const uint2*)lus;
    uint2* d2 = (uint2*)(vt + (size_t)n0 * RW);
    if (t < 192) d2[t] = lu2[t];
    if (e_ok) rank[e] = rv;
}

__global__ __launch_bounds__(256) void uls_alloc(
    const unsigned* __restrict__ deg, unsigned* __restrict__ start,
    unsigned* __restrict__ counter)
{
    __shared__ unsigned s[256];
    __shared__ unsigned base;
    int t = threadIdx.x;
    int n = blockIdx.x * 256 + t;
    unsigned d = (n < N) ? deg[n] : 0u;
    s[t] = d;
    __syncthreads();
    for (int off = 1; off < 256; off <<= 1) {
        unsigned v = (t >= off) ? s[t - off] : 0u;
        __syncthreads();
        s[t] += v;
        __syncthreads();
    }
    if (t == 255) base = atomicAdd(counter, s[255]);
    __syncthreads();
    if (n < N) start[n] = base + (s[t] - d);
}

__global__ __launch_bounds__(256) void uls_fill(
    const int* __restrict__ faces, const unsigned* __restrict__ start,
    const unsigned* __restrict__ rank, int* __restrict__ adj)
{
    int e = blockIdx.x * 256 + threadIdx.x;
    if (e >= C3) return;
    int f = e / 3;
    int c = e - 3 * f;
    int a  = faces[3 * f + 0];
    int b  = faces[3 * f + 1];
    int cc = faces[3 * f + 2];
    int dst = (c == 0) ? a : (c == 1) ? b : cc;
    int p0  = (c == 0) ? b : a;
    int p1  = (c == 2) ? b : cc;
    unsigned p = start[dst] + rank[e];
    *(int2*)(adj + p) = make_int2(p0, p1);
}

__global__ __launch_bounds__(256) void uls_gather_csr(
    const unsigned short* __restrict__ vt, const int* __restrict__ adj,
    const unsigned* __restrict__ start, const unsigned* __restrict__ deg,
    float* __restrict__ out)
{
    __shared__ float lds[16 * 65];
    int t = threadIdx.x;
    int q = t & 3;
    int v = t >> 2;
    int n = blockIdx.x * 64 + v;
    bool n_ok = (n < N);
    unsigned d  = n_ok ? deg[n]   : 0u;
    unsigned s0 = n_ok ? start[n] : 0u;
    float acc[3][4] = {{0,0,0,0},{0,0,0,0},{0,0,0,0}};
    unsigned j = 0;
    for (; j + 4 <= d; j += 4) {
        int2 p0 = *(const int2*)(adj + s0 + j);
        int2 p1 = *(const int2*)(adj + s0 + j + 2);
        acc_row(vt + (size_t)p0.x * RW, q, acc);
        acc_row(vt + (size_t)p0.y * RW, q, acc);
        acc_row(vt + (size_t)p1.x * RW, q, acc);
        acc_row(vt + (size_t)p1.y * RW, q, acc);
    }
    if (j < d) {
        int2 p0 = *(const int2*)(adj + s0 + j);
        acc_row(vt + (size_t)p0.x * RW, q, acc);
        acc_row(vt + (size_t)p0.y * RW, q, acc);
    }
    if (n_ok) {
        float self[3][4];
        const unsigned short* rs = vt + (size_t)n * RW;
#pragma unroll
        for (int cc = 0; cc < 3; ++cc) {
            uint2 u = *(const uint2*)(rs + cc * 16 + 4 * q);
            self[cc][0] = __uint_as_float(u.x << 16);
            self[cc][1] = __uint_as_float(u.x & 0xFFFF0000u);
            self[cc][2] = __uint_as_float(u.y << 16);
            self[cc][3] = __uint_as_float(u.y & 0xFFFF0000u);
        }
        float inv = 1.0f / fmaxf((float)d, 1.0f);
#pragma unroll
        for (int k = 0; k < 4; ++k) {
            float lx = acc[0][k] * inv - self[0][k];
            float ly = acc[1][k] * inv - self[1][k];
            float lz = acc[2][k] * inv - self[2][k];
            lds[(4 * q + k) * 65 + v] = sqrtf(lx * lx + ly * ly + lz * lz);
        }
    }
    __syncthreads();
    int vo = t & 63;
    int nn = blockIdx.x * 64 + vo;
    if (nn < N) {
#pragma unroll
        for (int k = 0; k < 4; ++k) {
            int bo = (t >> 6) + 4 * k;
            out[(size_t)bo * N + nn] = lds[bo * 65 + vo];
        }
    }
}

// ================= launcher =================

extern "C" void kernel_launch(void* const* d_in, const int* in_sizes, int n_in,
                              void* d_out, int out_size, void* d_ws, size_t ws_size,
                              hipStream_t stream) {
    const float* vert  = (const float*)d_in[0];
    const int*   faces = (const int*)d_in[1];
    float* out = (float*)d_out;
    char* ws = (char*)d_ws;

    if (ws_size >= D_NEED) {
        unsigned short* vt  = (unsigned short*)(ws + D_VT);
        unsigned*       deg = (unsigned*)(ws + D_DEG);
        long long*      adj = (long long*)(ws + D_ADJ);
        uls_zero_deg<<<(DEG_U4 + 255) / 256, 256, 0, stream>>>((uint4*)deg);
        uls_setup_direct<<<SETUP_G, 256, 0, stream>>>(vert, faces, vt, deg, adj);
        uls_gather_direct<<<(N + 63) / 64, 256, 0, stream>>>(vt, adj, deg, out);
    } else {
        // CSR pipeline (proven at 264.6 us)
        unsigned short* vt      = (unsigned short*)(ws + C_VT);
        int*            adj     = (int*)(ws + C_ADJ);
        unsigned*       deg     = (unsigned*)(ws + C_DEG);
        unsigned*       counter = (unsigned*)(ws + C_CNT);
        unsigned*       start   = (unsigned*)(ws + C_STA);
        unsigned*       rank    = (unsigned*)(ws + C_RNK);
        hipMemsetAsync(ws + C_DEG, 0, (C_CNT + 256) - C_DEG, stream);
        uls_setup_csr<<<N / 16, 256, 0, stream>>>(vert, faces, vt, deg, rank);
        uls_alloc<<<(N + 255) / 256, 256, 0, stream>>>(deg, start, counter);
        uls_fill<<<(C3 + 255) / 256, 256, 0, stream>>>(faces, start, rank, adj);
        uls_gather_csr<<<(N + 63) / 64, 256, 0, stream>>>(vt, adj, start, deg, out);
    }
}

// Round 8
// 228.841 us; speedup vs baseline: 1.0585x; 1.0011x over previous
//
#include <hip/hip_runtime.h>

// Problem constants (fixed by the reference file).
static constexpr int B = 16;
static constexpr int N = 250000;   // 15625 * 16
static constexpr int F = 500000;
static constexpr int C3 = 3 * F;   // corners = 1,500,000
static constexpr int E = 6 * F;    // directed edges (CSR fallback)
static constexpr int RW = 48;      // ushorts per vt row: 3 comps * 16 batches (96 B)
static constexpr int CAP = 24;     // pair capacity/vertex (Poisson(6); P(>=24) ~ 3e-11)
static constexpr int PF  = 12;     // gather prefetch depth (P(pairs>12) ~ 0.8%)
static constexpr int SLICE = N / 8;          // 31250 vertices per XCD slice
static constexpr int SETUP_G = ((F + 255) / 256) * 8;   // 1954 * 8 = 15632 blocks
static_assert(SETUP_G >= N / 16, "setup grid must still cover the transpose");

// deg zero-fill: N uints = 1,000,000 B = 62,500 uint4
static constexpr int DEG_U4 = (N * 4) / 16;  // 62500
static_assert(DEG_U4 * 16 == N * 4, "deg must be uint4-divisible");

// ---- DIRECT layout (bytes): vt | deg (compact) | adjp PLANE-MAJOR ----
// adjp[pi * N + n] (pi < CAP).
// nt discipline (R5-R8 lessons):
//   - vert loads: nt (read-once streaming)           -> setup win (R7)
//   - vt STORE: NORMAL. R7 made it nt and gather's FETCH_SIZE hit 258 MB on a
//     24 MB array — nt kept vt out of L3, so 3M random row-reads went to HBM.
//     vt is written once but READ 12x: it must be cache-resident.
//   - adj stores: normal (multi-write/line, L2 merges; nt regressed in R5)
//   - gather adj/deg loads + out stores: nt (read-once/write-once)
static constexpr size_t D_VT  = 0;                                   // 24,000,000
static constexpr size_t D_DEG = (size_t)N * RW * 2;                  // 24,000,000 (+1 MB)
static constexpr size_t D_ADJ = D_DEG + (size_t)N * 4;               // 25,000,000
static constexpr size_t D_NEED = D_ADJ + (size_t)N * CAP * 8;        // 73,000,000

// ---- CSR fallback layout (R5-proven structure) ----
static constexpr size_t C_VT  = 0;
static constexpr size_t C_ADJ = (size_t)N * RW * 2;
static constexpr size_t C_DEG = C_ADJ + (size_t)E * sizeof(int);
static constexpr size_t C_CNT = C_DEG + (size_t)N * sizeof(unsigned);
static constexpr size_t C_STA = C_CNT + 256;
static constexpr size_t C_RNK = C_STA + (size_t)N * sizeof(unsigned);

__device__ __forceinline__ unsigned short f2bf(float f) {
    unsigned u = __float_as_uint(f);
    return (unsigned short)((u + 0x7FFFu + ((u >> 16) & 1u)) >> 16);  // RNE
}

__device__ __forceinline__ long long pack_pair(int p0, int p1) {
    return (long long)((unsigned long long)(unsigned)p0 |
                       ((unsigned long long)(unsigned)p1 << 32));
}

// Zero deg with a compute kernel (1 MB), not hipMemsetAsync (SDMA, ~13 us).
__global__ __launch_bounds__(256) void uls_zero_deg(uint4* __restrict__ degv) {
    for (int i = blockIdx.x * 256 + threadIdx.x; i < DEG_U4;
         i += gridDim.x * 256)
        degv[i] = make_uint4(0u, 0u, 0u, 0u);
}

// ================= DIRECT path =================

// Fused: transpose (B,N,3)fp32 -> (N,3,16)bf16  +  slice-partitioned corner alloc.
// slice = blockIdx % 8: all atomics/writes to a given deg/adj line issue from
// ONE XCD under the default round-robin blockIdx->XCD map (R1: 120 -> 97 us).
__global__ __launch_bounds__(256) void uls_setup_direct(
    const float* __restrict__ vert, const int* __restrict__ faces,
    unsigned short* __restrict__ vt, unsigned* __restrict__ deg,
    long long* __restrict__ adjp)
{
    __shared__ unsigned short lus[16 * RW];
    int t   = threadIdx.x;
    int bid = blockIdx.x;
    int s   = bid & 7;            // vertex slice (XCD-aligned under round-robin)
    int g   = bid >> 3;           // rank within slice-group
    int f   = g * 256 + t;        // one face per thread per slice-scan
    bool f_ok = (f < F);
    unsigned lo = (unsigned)(s * SLICE);

    int a = 0, b2 = 0, c2 = 0;
    if (f_ok) {                   // faces: normal loads (re-read 8x, L3-hot)
        a  = faces[3 * f + 0];
        b2 = faces[3 * f + 1];
        c2 = faces[3 * f + 2];
    }
    bool k0 = f_ok && ((unsigned)a  - lo < (unsigned)SLICE);
    bool k1 = f_ok && ((unsigned)b2 - lo < (unsigned)SLICE);
    bool k2 = f_ok && ((unsigned)c2 - lo < (unsigned)SLICE);
    unsigned r0 = 0, r1 = 0, r2 = 0;
    if (k0) r0 = atomicAdd(&deg[a],  2u);   // slot allocator (compact counters)
    if (k1) r1 = atomicAdd(&deg[b2], 2u);
    if (k2) r2 = atomicAdd(&deg[c2], 2u);

    // transpose part (blocks < N/16); atomic latency hides behind this.
    // vert loads nt (read-once). vt store NORMAL (re-read 12x by gather!).
    if (bid < N / 16) {
        int n0 = bid * 16;
        int bb = t >> 4, v = t & 15;
        const float* sp = vert + (size_t)bb * (N * 3) + (size_t)(n0 + v) * 3;
        lus[v * RW + 0 * 16 + bb] = f2bf(__builtin_nontemporal_load(&sp[0]));
        lus[v * RW + 1 * 16 + bb] = f2bf(__builtin_nontemporal_load(&sp[1]));
        lus[v * RW + 2 * 16 + bb] = f2bf(__builtin_nontemporal_load(&sp[2]));
        __syncthreads();
        const uint2* lu2 = (const uint2*)lus;
        uint2* d2 = (uint2*)(vt + (size_t)n0 * RW);
        if (t < 192) d2[t] = lu2[t];          // coalesced 1536 B per block
    }

    // pair writes last, NORMAL stores (multi-write/line: let L2 merge them)
    if (k0) { unsigned pi = r0 >> 1; if (pi < (unsigned)CAP)
        adjp[(size_t)pi * N + a]  = pack_pair(b2, c2); }
    if (k1) { unsigned pi = r1 >> 1; if (pi < (unsigned)CAP)
        adjp[(size_t)pi * N + b2] = pack_pair(a, c2); }
    if (k2) { unsigned pi = r2 >> 1; if (pi < (unsigned)CAP)
        adjp[(size_t)pi * N + c2] = pack_pair(a, b2); }
}

// 4 lanes per vertex; lane q owns batches 4q..4q+3 via uint2 (8 B) loads.
__device__ __forceinline__ void acc_row(const unsigned short* __restrict__ r,
                                        int q, float (&acc)[3][4]) {
#pragma unroll
    for (int cc = 0; cc < 3; ++cc) {
        uint2 u = *(const uint2*)(r + cc * 16 + 4 * q);
        acc[cc][0] += __uint_as_float(u.x << 16);
        acc[cc][1] += __uint_as_float(u.x & 0xFFFF0000u);
        acc[cc][2] += __uint_as_float(u.y << 16);
        acc[cc][3] += __uint_as_float(u.y & 0xFFFF0000u);
    }
}

// Up-front predicated adj plane loads (one L3 round-trip), rows streamed behind.
__global__ __launch_bounds__(256) void uls_gather_direct(
    const unsigned short* __restrict__ vt, const long long* __restrict__ adjp,
    const unsigned* __restrict__ deg, float* __restrict__ out)
{
    __shared__ float lds[16 * 65];
    int t = threadIdx.x;
    int q = t & 3;
    int v = t >> 2;
    int n = blockIdx.x * 64 + v;
    bool n_ok = (n < N);

    unsigned d = n_ok ? __builtin_nontemporal_load(&deg[n]) : 0u;
    if (d > 2u * CAP) d = 2u * CAP;
    unsigned pairs = d >> 1;              // <= 24
    const long long* ap = adjp + n;       // this vertex's column

    // self row hoisted: 3 more loads in flight during the gather loop
    float self[3][4] = {{0,0,0,0},{0,0,0,0},{0,0,0,0}};
    if (n_ok) {
        const unsigned short* rs = vt + (size_t)n * RW;
#pragma unroll
        for (int cc = 0; cc < 3; ++cc) {
            uint2 u = *(const uint2*)(rs + cc * 16 + 4 * q);
            self[cc][0] = __uint_as_float(u.x << 16);
            self[cc][1] = __uint_as_float(u.x & 0xFFFF0000u);
            self[cc][2] = __uint_as_float(u.y << 16);
            self[cc][3] = __uint_as_float(u.y & 0xFFFF0000u);
        }
    }

    // predicated up-front adj loads (exec-masked: off lanes issue nothing)
    long long pv[PF];
#pragma unroll
    for (int j = 0; j < PF; ++j)
        pv[j] = (j < (int)pairs)
              ? __builtin_nontemporal_load(&ap[(size_t)j * N]) : 0ll;

    float acc[3][4] = {{0,0,0,0},{0,0,0,0},{0,0,0,0}};
#pragma unroll
    for (int j = 0; j < PF; ++j) {
        if (j < (int)pairs) {
            acc_row(vt + (size_t)(unsigned)pv[j] * RW, q, acc);
            acc_row(vt + (size_t)(unsigned)(pv[j] >> 32) * RW, q, acc);
        }
    }
    for (unsigned j = PF; j < pairs; ++j) {     // Poisson tail, P ~ 0.8%
        long long v0 = __builtin_nontemporal_load(&ap[(size_t)j * N]);
        acc_row(vt + (size_t)(unsigned)v0 * RW, q, acc);
        acc_row(vt + (size_t)(unsigned)(v0 >> 32) * RW, q, acc);
    }

    if (n_ok) {
        float inv = 1.0f / fmaxf((float)d, 1.0f);
#pragma unroll
        for (int k = 0; k < 4; ++k) {
            float lx = acc[0][k] * inv - self[0][k];
            float ly = acc[1][k] * inv - self[1][k];
            float lz = acc[2][k] * inv - self[2][k];
            lds[(4 * q + k) * 65 + v] = sqrtf(lx * lx + ly * ly + lz * lz);
        }
    }
    __syncthreads();
    int vo = t & 63;
    int nn = blockIdx.x * 64 + vo;
    if (nn < N) {
#pragma unroll
        for (int k = 0; k < 4; ++k) {
            int bo = (t >> 6) + 4 * k;
            __builtin_nontemporal_store(lds[bo * 65 + vo],
                                        &out[(size_t)bo * N + nn]);
        }
    }
}

// ================= CSR fallback (used only if ws < 73 MB) =================

__global__ __launch_bounds__(256) void uls_setup_csr(
    const float* __restrict__ vert, const int* __restrict__ faces,
    unsigned short* __restrict__ vt, unsigned* __restrict__ deg,
    unsigned* __restrict__ rank)
{
    __shared__ unsigned short lus[16 * RW];
    int t = threadIdx.x;
    int n0 = blockIdx.x * 16;
    int b = t >> 4, v = t & 15;
    int e = blockIdx.x * 256 + t;
    unsigned rv = 0;
    bool e_ok = (e < C3);
    int dst = e_ok ? faces[e] : 0;
    if (e_ok) rv = atomicAdd(&deg[dst], 2u);
    const float* s = vert + (size_t)b * (N * 3) + (size_t)(n0 + v) * 3;
    lus[v * RW + 0 * 16 + b] = f2bf(s[0]);
    lus[v * RW + 1 * 16 + b] = f2bf(s[1]);
    lus[v * RW + 2 * 16 + b] = f2bf(s[2]);
    __syncthreads();
    const uint2* lu2 = (const uint2*)lus;
    uint2* d2 = (uint2*)(vt + (size_t)n0 * RW);
    if (t < 192) d2[t] = lu2[t];
    if (e_ok) rank[e] = rv;
}

__global__ __launch_bounds__(256) void uls_alloc(
    const unsigned* __restrict__ deg, unsigned* __restrict__ start,
    unsigned* __restrict__ counter)
{
    __shared__ unsigned s[256];
    __shared__ unsigned base;
    int t = threadIdx.x;
    int n = blockIdx.x * 256 + t;
    unsigned d = (n < N) ? deg[n] : 0u;
    s[t] = d;
    __syncthreads();
    for (int off = 1; off < 256; off <<= 1) {
        unsigned v = (t >= off) ? s[t - off] : 0u;
        __syncthreads();
        s[t] += v;
        __syncthreads();
    }
    if (t == 255) base = atomicAdd(counter, s[255]);
    __syncthreads();
    if (n < N) start[n] = base + (s[t] - d);
}

__global__ __launch_bounds__(256) void uls_fill(
    const int* __restrict__ faces, const unsigned* __restrict__ start,
    const unsigned* __restrict__ rank, int* __restrict__ adj)
{
    int e = blockIdx.x * 256 + threadIdx.x;
    if (e >= C3) return;
    int f = e / 3;
    int c = e - 3 * f;
    int a  = faces[3 * f + 0];
    int b  = faces[3 * f + 1];
    int cc = faces[3 * f + 2];
    int dst = (c == 0) ? a : (c == 1) ? b : cc;
    int p0  = (c == 0) ? b : a;
    int p1  = (c == 2) ? b : cc;
    unsigned p = start[dst] + rank[e];
    *(int2*)(adj + p) = make_int2(p0, p1);
}

__global__ __launch_bounds__(256) void uls_gather_csr(
    const unsigned short* __restrict__ vt, const int* __restrict__ adj,
    const unsigned* __restrict__ start, const unsigned* __restrict__ deg,
    float* __restrict__ out)
{
    __shared__ float lds[16 * 65];
    int t = threadIdx.x;
    int q = t & 3;
    int v = t >> 2;
    int n = blockIdx.x * 64 + v;
    bool n_ok = (n < N);
    unsigned d  = n_ok ? deg[n]   : 0u;
    unsigned s0 = n_ok ? start[n] : 0u;
    float acc[3][4] = {{0,0,0,0},{0,0,0,0},{0,0,0,0}};
    unsigned j = 0;
    for (; j + 4 <= d; j += 4) {
        int2 p0 = *(const int2*)(adj + s0 + j);
        int2 p1 = *(const int2*)(adj + s0 + j + 2);
        acc_row(vt + (size_t)p0.x * RW, q, acc);
        acc_row(vt + (size_t)p0.y * RW, q, acc);
        acc_row(vt + (size_t)p1.x * RW, q, acc);
        acc_row(vt + (size_t)p1.y * RW, q, acc);
    }
    if (j < d) {
        int2 p0 = *(const int2*)(adj + s0 + j);
        acc_row(vt + (size_t)p0.x * RW, q, acc);
        acc_row(vt + (size_t)p0.y * RW, q, acc);
    }
    if (n_ok) {
        float self[3][4];
        const unsigned short* rs = vt + (size_t)n * RW;
#pragma unroll
        for (int cc = 0; cc < 3; ++cc) {
            uint2 u = *(const uint2*)(rs + cc * 16 + 4 * q);
            self[cc][0] = __uint_as_float(u.x << 16);
            self[cc][1] = __uint_as_float(u.x & 0xFFFF0000u);
            self[cc][2] = __uint_as_float(u.y << 16);
            self[cc][3] = __uint_as_float(u.y & 0xFFFF0000u);
        }
        float inv = 1.0f / fmaxf((float)d, 1.0f);
#pragma unroll
        for (int k = 0; k < 4; ++k) {
            float lx = acc[0][k] * inv - self[0][k];
            float ly = acc[1][k] * inv - self[1][k];
            float lz = acc[2][k] * inv - self[2][k];
            lds[(4 * q + k) * 65 + v] = sqrtf(lx * lx + ly * ly + lz * lz);
        }
    }
    __syncthreads();
    int vo = t & 63;
    int nn = blockIdx.x * 64 + vo;
    if (nn < N) {
#pragma unroll
        for (int k = 0; k < 4; ++k) {
            int bo = (t >> 6) + 4 * k;
            out[(size_t)bo * N + nn] = lds[bo * 65 + vo];
        }
    }
}

// ================= launcher =================

extern "C" void kernel_launch(void* const* d_in, const int* in_sizes, int n_in,
                              void* d_out, int out_size, void* d_ws, size_t ws_size,
                              hipStream_t stream) {
    const float* vert  = (const float*)d_in[0];
    const int*   faces = (const int*)d_in[1];
    float* out = (float*)d_out;
    char* ws = (char*)d_ws;

    if (ws_size >= D_NEED) {
        unsigned short* vt  = (unsigned short*)(ws + D_VT);
        unsigned*       deg = (unsigned*)(ws + D_DEG);
        long long*      adj = (long long*)(ws + D_ADJ);
        uls_zero_deg<<<(DEG_U4 + 255) / 256, 256, 0, stream>>>((uint4*)deg);
        uls_setup_direct<<<SETUP_G, 256, 0, stream>>>(vert, faces, vt, deg, adj);
        uls_gather_direct<<<(N + 63) / 64, 256, 0, stream>>>(vt, adj, deg, out);
    } else {
        // CSR pipeline (proven at 264.6 us)
        unsigned short* vt      = (unsigned short*)(ws + C_VT);
        int*            adj     = (int*)(ws + C_ADJ);
        unsigned*       deg     = (unsigned*)(ws + C_DEG);
        unsigned*       counter = (unsigned*)(ws + C_CNT);
        unsigned*       start   = (unsigned*)(ws + C_STA);
        unsigned*       rank    = (unsigned*)(ws + C_RNK);
        hipMemsetAsync(ws + C_DEG, 0, (C_CNT + 256) - C_DEG, stream);
        uls_setup_csr<<<N / 16, 256, 0, stream>>>(vert, faces, vt, deg, rank);
        uls_alloc<<<(N + 255) / 256, 256, 0, stream>>>(deg, start, counter);
        uls_fill<<<(C3 + 255) / 256, 256, 0, stream>>>(faces, start, rank, adj);
        uls_gather_csr<<<(N + 63) / 64, 256, 0, stream>>>(vt, adj, start, deg, out);
    }
}